// Round 10
// baseline (5915.631 us; speedup 1.0000x reference)
//
#include <hip/hip_runtime.h>

#define BB   4
#define NN   256
#define TT   4096
#define DD   128      // SIM_DIM
#define LK   101      // LOOKUP
#define PADK 50
#define OD   128      // OUT_DIM
#define ROWS 164      // 64 + LK - 1 rows of halo'd proj window
#define RSTR 33       // f32 band: row stride in float4 units (132 floats, +4 pad)
#define P16W 68       // f16 band: row stride in u32 units (64 data + 4 pad = 272 B)
#define CPB  8        // pool chunks per block
#define FS_STR 68     // proj fs row stride (64 t + 4 pad)
#define WB_STR 132    // proj wbuf row stride (128 d + 4 pad)

typedef float vfloat4 __attribute__((ext_vector_type(4)));
typedef _Float16 half2v __attribute__((ext_vector_type(2)));

union U32H2 { unsigned int u; half2v h; };

__device__ inline float fdot2f(half2v a, half2v b, float c) {
#if __has_builtin(__builtin_amdgcn_fdot2)
  return __builtin_amdgcn_fdot2(a, b, c, false);
#else
  return c + (float)a.x * (float)b.x + (float)a.y * (float)b.y;
#endif
}

__device__ inline unsigned int pk16(float lo, float hi) {
  return __builtin_bit_cast(unsigned int, __builtin_amdgcn_cvt_pkrtz(lo, hi));
}

// ---------------- kernel 1: one-time weight transposes ----------------
__global__ __launch_bounds__(256) void transpose_w_kernel(
    const float* __restrict__ w_proj, const float* __restrict__ w_fc,
    float* __restrict__ w_t, float* __restrict__ wfc_t) {
  int idx = blockIdx.x * 256 + threadIdx.x;
  int stride = gridDim.x * 256;
  for (int i = idx; i < DD * NN; i += stride) {
    int d = i / NN, n = i - d * NN;
    w_t[n * DD + d] = w_proj[i];
  }
  for (int i = idx; i < OD * LK; i += stride) {
    int o = i / LK, j = i - o * LK;
    wfc_t[j * OD + o] = w_fc[i];
  }
}

// ---------------- kernel 2: spatial mean-pool (HBM-bound) ----------------
__global__ __launch_bounds__(256) void pool_kernel(
    const float* __restrict__ x, float* __restrict__ feat, int rep) {
  __shared__ float part[2][768];
  int tid = threadIdx.x;
  for (int rp = 0; rp < rep; ++rp) {
    for (int c = 0; c < CPB; ++c) {
      size_t ck = (size_t)blockIdx.x * CPB + c;
      const vfloat4* x4 = (const vfloat4*)(x + ck * 3072);
      float* pb = part[c & 1];
#pragma unroll
      for (int p = 0; p < 3; ++p) {
        vfloat4 v = __builtin_nontemporal_load(&x4[p * 256 + tid]);
        pb[p * 256 + tid] = (v.x + v.y) + (v.z + v.w);
      }
      __syncthreads();
      if (tid < 64) {
        float s0 = 0.f, s1 = 0.f;
        const float* pp = pb + tid * 12;
#pragma unroll
        for (int i = 0; i < 6; ++i) { s0 += pp[i]; s1 += pp[6 + i]; }
        feat[ck * 64 + tid] = (s0 + s1) * (1.0f / 48.0f);
      }
    }
    __syncthreads();
  }
}

// ---------------- kernel 3: projection + L2 normalize (v3, R8) ----------------
__global__ __launch_bounds__(512, 1) void proj_kernel(
    const float* __restrict__ feat, const float* __restrict__ w_t,
    float* __restrict__ projn, int rep) {
  extern __shared__ float smemP[];
  float* fs   = smemP;               // [256 n][68]
  float* wbuf = smemP + NN * FS_STR; // [64 n][132]
  int b = blockIdx.x >> 6;
  int t0 = (blockIdx.x & 63) << 6;
  int tid = threadIdx.x;
  int td = tid & 31, tt = tid >> 5;

  for (int rp = 0; rp < rep; ++rp) {
    float acc[4][4];
#pragma unroll
    for (int i = 0; i < 4; ++i)
#pragma unroll
      for (int j = 0; j < 4; ++j) acc[i][j] = 0.f;

    for (int c = 0; c < 4; ++c) {
      if (c) __syncthreads();
#pragma unroll
      for (int k = 0; k < 4; ++k) {
        int slot = tid + k * 512;
        int n = slot >> 5, d4 = slot & 31;
        *(float4*)(wbuf + n * WB_STR + d4 * 4) =
            *(const float4*)(w_t + (size_t)(c * 64 + n) * DD + d4 * 4);
      }
      if (c == 0) {
#pragma unroll
        for (int k = 0; k < 8; ++k) {
          int slot = tid + k * 512;
          int n = slot >> 4, t4 = slot & 15;
          *(float4*)(fs + n * FS_STR + t4 * 4) =
              *(const float4*)(feat + ((size_t)(b * NN + n)) * TT + t0 + t4 * 4);
        }
      }
      __syncthreads();

      const float* fp = fs + (c * 64) * FS_STR + tt * 4;
      const float* wp = wbuf + td * 4;
#pragma unroll 4
      for (int n = 0; n < 64; ++n) {
        float4 f = *(const float4*)(fp + n * FS_STR);
        float4 wv = *(const float4*)(wp + n * WB_STR);
        float fa[4] = {f.x, f.y, f.z, f.w};
#pragma unroll
        for (int i = 0; i < 4; ++i) {
          acc[i][0] += fa[i] * wv.x;
          acc[i][1] += fa[i] * wv.y;
          acc[i][2] += fa[i] * wv.z;
          acc[i][3] += fa[i] * wv.w;
        }
      }
    }

    float s[4];
#pragma unroll
    for (int i = 0; i < 4; ++i)
      s[i] = acc[i][0] * acc[i][0] + acc[i][1] * acc[i][1] +
             acc[i][2] * acc[i][2] + acc[i][3] * acc[i][3];
#pragma unroll
    for (int m = 1; m < 32; m <<= 1) {
#pragma unroll
      for (int i = 0; i < 4; ++i) s[i] += __shfl_xor(s[i], m, 64);
    }
#pragma unroll
    for (int i = 0; i < 4; ++i) {
      float inv = 1.0f / fmaxf(sqrtf(s[i]), 1e-12f);
      float4 o;
      o.x = acc[i][0] * inv; o.y = acc[i][1] * inv;
      o.z = acc[i][2] * inv; o.w = acc[i][3] * inv;
      *(float4*)(projn + ((size_t)(b * TT + t0 + tt * 4 + i)) * DD + td * 4) = o;
    }
    __syncthreads();
  }
}

// ---------------- kernel 4a: band+FC, f16 P window (LDS-width fix) ----------------
// P staged as f16 (272 B/row): 16 b128 per s-row (was 32). Dot via v_dot2_f32_f16,
// f32 accumulate. Own row in 64 half2 VGPRs. FC phase unchanged (f32).
__global__ __launch_bounds__(512, 1) void band_fc_f16_kernel(
    const float* __restrict__ projn, const float* __restrict__ wfc_t,
    const float* __restrict__ b_fc, float* __restrict__ out, int rep) {
  extern __shared__ unsigned int smemF[];
  unsigned int* p16 = smemF;                       // [ROWS][68] u32 (f16 pairs)
  float* band = (float*)(smemF + ROWS * P16W);     // [64][101]
  int b = blockIdx.x >> 6;
  int t0 = (blockIdx.x & 63) << 6;
  int tid = threadIdx.x;

  for (int rp = 0; rp < rep; ++rp) {
    // stage P window as f16 (zero-fill OOB)
    const float4* pg = (const float4*)projn;
    for (int i = tid; i < ROWS * 32; i += 512) {
      int r = i >> 5, c = i & 31;
      int t = t0 + r - PADK;
      unsigned int w0 = 0, w1 = 0;
      if (t >= 0 && t < TT) {
        float4 v = pg[(((size_t)b * TT + t) << 5) + c];
        w0 = pk16(v.x, v.y);
        w1 = pk16(v.z, v.w);
      }
      p16[r * P16W + c * 2] = w0;
      p16[r * P16W + c * 2 + 1] = w1;
    }
    __syncthreads();

    int w = tid >> 6, tt = tid & 63;

    // own row -> 64 half2 regs
    half2v own2[64];
    {
      const uint4* prow = (const uint4*)(p16 + (tt + PADK) * P16W);
#pragma unroll
      for (int c = 0; c < 16; ++c) {
        uint4 v = prow[c];
        U32H2 u0, u1, u2, u3;
        u0.u = v.x; u1.u = v.y; u2.u = v.z; u3.u = v.w;
        own2[c * 4 + 0] = u0.h; own2[c * 4 + 1] = u1.h;
        own2[c * 4 + 2] = u2.h; own2[c * 4 + 3] = u3.h;
      }
    }

    int s0 = w * 21;
    int sEnd = (s0 + 21 < ROWS) ? (s0 + 21) : ROWS;
    for (int s = s0; s < sEnd; ++s) {
      const uint4* ps = (const uint4*)(p16 + s * P16W);
      float a0 = 0.f, a1 = 0.f, a2 = 0.f, a3 = 0.f;
#pragma unroll
      for (int c = 0; c < 16; ++c) {
        uint4 v = ps[c];                 // wave-uniform -> LDS broadcast
        U32H2 u0, u1, u2, u3;
        u0.u = v.x; u1.u = v.y; u2.u = v.z; u3.u = v.w;
        a0 = fdot2f(own2[c * 4 + 0], u0.h, a0);
        a1 = fdot2f(own2[c * 4 + 1], u1.h, a1);
        a2 = fdot2f(own2[c * 4 + 2], u2.h, a2);
        a3 = fdot2f(own2[c * 4 + 3], u3.h, a3);
      }
      int j = s - tt;
      if (j >= 0 && j < LK) band[tt * LK + j] = (a0 + a1) + (a2 + a3);
    }
    __syncthreads();

    // FC + ReLU (f32)
    int o0u = __builtin_amdgcn_readfirstlane((tid >> 6) * 16);
    float acc[16];
    const float4* bf4 = (const float4*)(b_fc + o0u);
#pragma unroll
    for (int k = 0; k < 4; ++k) {
      float4 bv = bf4[k];
      acc[4 * k + 0] = bv.x; acc[4 * k + 1] = bv.y;
      acc[4 * k + 2] = bv.z; acc[4 * k + 3] = bv.w;
    }
#pragma unroll 2
    for (int j = 0; j < LK; ++j) {
      float bv = band[tt * LK + j];
      const float4* wr = (const float4*)(wfc_t + j * OD + o0u);
#pragma unroll
      for (int k = 0; k < 4; ++k) {
        float4 wv = wr[k];
        acc[4 * k + 0] += wv.x * bv;
        acc[4 * k + 1] += wv.y * bv;
        acc[4 * k + 2] += wv.z * bv;
        acc[4 * k + 3] += wv.w * bv;
      }
    }
    float4* og = (float4*)(out + ((size_t)(b * TT + t0 + tt)) * OD + o0u);
#pragma unroll
    for (int k = 0; k < 4; ++k) {
      float4 o;
      o.x = fmaxf(acc[4 * k + 0], 0.f);
      o.y = fmaxf(acc[4 * k + 1], 0.f);
      o.z = fmaxf(acc[4 * k + 2], 0.f);
      o.w = fmaxf(acc[4 * k + 3], 0.f);
      og[k] = o;
    }
    __syncthreads();
  }
}

// ---------------- kernel 4b: band+FC, f32 (R8 exact) — probe comparator ----------------
__global__ __launch_bounds__(512, 1) void band_fc_f32_kernel(
    const float* __restrict__ projn, const float* __restrict__ wfc_t,
    const float* __restrict__ b_fc, float* __restrict__ out, int rep) {
  extern __shared__ float4 smemC[];
  float4* p4 = smemC;
  float* band = (float*)(smemC + ROWS * RSTR);
  int b = blockIdx.x >> 6;
  int t0 = (blockIdx.x & 63) << 6;
  int tid = threadIdx.x;

  for (int rp = 0; rp < rep; ++rp) {
    const float4* pg = (const float4*)projn;
    for (int i = tid; i < ROWS * 32; i += 512) {
      int r = i >> 5, c = i & 31;
      int t = t0 + r - PADK;
      float4 v = make_float4(0.f, 0.f, 0.f, 0.f);
      if (t >= 0 && t < TT) v = pg[(((size_t)b * TT + t) << 5) + c];
      p4[r * RSTR + c] = v;
    }
    __syncthreads();

    int w = tid >> 6, tt = tid & 63;
    float4 own[32];
#pragma unroll
    for (int c = 0; c < 32; ++c) own[c] = p4[(tt + PADK) * RSTR + c];

    int s0 = w * 21;
    int sEnd = (s0 + 21 < ROWS) ? (s0 + 21) : ROWS;
    for (int s = s0; s < sEnd; ++s) {
      float a0 = 0.f, a1 = 0.f, a2 = 0.f, a3 = 0.f;
#pragma unroll
      for (int c = 0; c < 32; ++c) {
        float4 ov = p4[s * RSTR + c];
        a0 += own[c].x * ov.x;
        a1 += own[c].y * ov.y;
        a2 += own[c].z * ov.z;
        a3 += own[c].w * ov.w;
      }
      int j = s - tt;
      if (j >= 0 && j < LK) band[tt * LK + j] = (a0 + a1) + (a2 + a3);
    }
    __syncthreads();

    int o0u = __builtin_amdgcn_readfirstlane((tid >> 6) * 16);
    float acc[16];
    const float4* bf4 = (const float4*)(b_fc + o0u);
#pragma unroll
    for (int k = 0; k < 4; ++k) {
      float4 bv = bf4[k];
      acc[4 * k + 0] = bv.x; acc[4 * k + 1] = bv.y;
      acc[4 * k + 2] = bv.z; acc[4 * k + 3] = bv.w;
    }
#pragma unroll 2
    for (int j = 0; j < LK; ++j) {
      float bv = band[tt * LK + j];
      const float4* wr = (const float4*)(wfc_t + j * OD + o0u);
#pragma unroll
      for (int k = 0; k < 4; ++k) {
        float4 wv = wr[k];
        acc[4 * k + 0] += wv.x * bv;
        acc[4 * k + 1] += wv.y * bv;
        acc[4 * k + 2] += wv.z * bv;
        acc[4 * k + 3] += wv.w * bv;
      }
    }
    float4* og = (float4*)(out + ((size_t)(b * TT + t0 + tt)) * OD + o0u);
#pragma unroll
    for (int k = 0; k < 4; ++k) {
      float4 o;
      o.x = fmaxf(acc[4 * k + 0], 0.f);
      o.y = fmaxf(acc[4 * k + 1], 0.f);
      o.z = fmaxf(acc[4 * k + 2], 0.f);
      o.w = fmaxf(acc[4 * k + 3], 0.f);
      og[k] = o;
    }
    __syncthreads();
  }
}

extern "C" void kernel_launch(void* const* d_in, const int* in_sizes, int n_in,
                              void* d_out, int out_size, void* d_ws, size_t ws_size,
                              hipStream_t stream) {
  const float* x      = (const float*)d_in[0];
  const float* w_proj = (const float*)d_in[1];
  const float* w_fc   = (const float*)d_in[2];
  const float* b_fc   = (const float*)d_in[3];
  float* out = (float*)d_out;

  char* ws = (char*)d_ws;
  float* feat  = (float*)ws;                                    // 16,777,216 B
  float* projn = (float*)(ws + 16777216);                       //  8,388,608 B
  float* w_t   = (float*)(ws + 16777216 + 8388608);             //    131,072 B
  float* wfc_t = (float*)(ws + 16777216 + 8388608 + 131072);    //     51,712 B
  float* S     = (float*)(ws + 16777216 + 8388608 + 131072 + 51712); // probe sink 8,388,608 B
  size_t need_probe = 16777216ull + 8388608 + 131072 + 51712 + 8388608;

  size_t smP = (size_t)(NN * FS_STR + 64 * WB_STR) * sizeof(float);                    // 103,424 B
  size_t smC = (size_t)ROWS * RSTR * sizeof(float4) + (size_t)64 * LK * sizeof(float); // 112,448 B
  size_t smF = (size_t)ROWS * P16W * sizeof(int) + (size_t)64 * LK * sizeof(float);    //  70,464 B
  (void)hipFuncSetAttribute((const void*)proj_kernel,
                      hipFuncAttributeMaxDynamicSharedMemorySize, (int)smP);
  (void)hipFuncSetAttribute((const void*)band_fc_f32_kernel,
                      hipFuncAttributeMaxDynamicSharedMemorySize, (int)smC);
  (void)hipFuncSetAttribute((const void*)band_fc_f16_kernel,
                      hipFuncAttributeMaxDynamicSharedMemorySize, (int)smF);

  // real path
  transpose_w_kernel<<<64, 256, 0, stream>>>(w_proj, w_fc, w_t, wfc_t);
  pool_kernel<<<(BB * NN * TT) / (64 * CPB), 256, 0, stream>>>(x, feat, 1);
  proj_kernel<<<BB * (TT / 64), 512, smP, stream>>>(feat, w_t, projn, 1);
  band_fc_f16_kernel<<<BB * (TT / 64), 512, smF, stream>>>(projn, wfc_t, b_fc, out, 1);

  // measurement probes (idempotent; scratch sinks; skipped if ws too small)
  if (ws_size >= need_probe) {
    pool_kernel<<<(BB * NN * TT) / (64 * CPB), 256, 0, stream>>>(x, feat, 6);
    proj_kernel<<<BB * (TT / 64), 512, smP, stream>>>(feat, w_t, projn, 100);
    band_fc_f16_kernel<<<BB * (TT / 64), 512, smF, stream>>>(projn, wfc_t, b_fc, S, 60);
    band_fc_f32_kernel<<<BB * (TT / 64), 512, smC, stream>>>(projn, wfc_t, b_fc, S, 40);
  }
}

// Round 11
// 215.370 us; speedup vs baseline: 27.4673x; 27.4673x over previous
//
#include <hip/hip_runtime.h>

#define BB   4
#define NN   256
#define TT   4096
#define DD   128      // SIM_DIM
#define LK   101      // LOOKUP
#define PADK 50
#define OD   128      // OUT_DIM
#define ROWS 164      // 64 + LK - 1 rows of halo'd proj window
#define RSTR 33       // band: row stride in float4 units (132 floats, +4 pad)
#define FS_STR 68     // proj fs row stride (64 t + 4 pad)
#define WB_STR 132    // proj wbuf row stride (128 d + 4 pad)

typedef float vfloat4 __attribute__((ext_vector_type(4)));

// ---------------- kernel 1: one-time weight transposes ----------------
__global__ __launch_bounds__(256) void transpose_w_kernel(
    const float* __restrict__ w_proj, const float* __restrict__ w_fc,
    float* __restrict__ w_t, float* __restrict__ wfc_t) {
  int idx = blockIdx.x * 256 + threadIdx.x;
  int stride = gridDim.x * 256;
  for (int i = idx; i < DD * NN; i += stride) {
    int d = i / NN, n = i - d * NN;
    w_t[n * DD + d] = w_proj[i];
  }
  for (int i = idx; i < OD * LK; i += stride) {
    int o = i / LK, j = i - o * LK;
    wfc_t[j * OD + o] = w_fc[i];
  }
}

// ---------------- kernel 2: spatial mean-pool v2 (max-MLP, 1 barrier) ----------------
// 8192 blocks x 256 thr; block = 512 rows (6144 float4, 98.3 KB, fully coalesced).
// 24 NT loads issued back-to-back per thread (24-deep vmcnt queue), register
// reduce, ONE LDS transpose (+13-pad: 2-way max on reduce reads), one barrier.
__global__ __launch_bounds__(256) void pool_kernel(
    const float* __restrict__ x, float* __restrict__ feat) {
  __shared__ float part[512 * 13];   // 26.6 KB
  int tid = threadIdx.x;
  const vfloat4* x4 = (const vfloat4*)x + (size_t)blockIdx.x * 6144;

  vfloat4 v[24];
#pragma unroll
  for (int k = 0; k < 24; ++k)
    v[k] = __builtin_nontemporal_load(&x4[tid + 256 * k]);

#pragma unroll
  for (int k = 0; k < 24; ++k) {
    int j = tid + 256 * k;
    int r = j / 12, i = j - r * 12;
    part[r * 13 + i] = (v[k].x + v[k].y) + (v[k].z + v[k].w);
  }
  __syncthreads();

  float* fo = feat + (size_t)blockIdx.x * 512;
#pragma unroll
  for (int q = 0; q < 2; ++q) {
    int o = tid + q * 256;
    const float* pp = part + o * 13;
    float a0 = 0.f, a1 = 0.f;
#pragma unroll
    for (int i = 0; i < 6; ++i) { a0 += pp[i]; a1 += pp[6 + i]; }
    fo[o] = (a0 + a1) * (1.0f / 48.0f);
  }
}

// ---------------- kernel 3: projection + L2 normalize (v3, R8 exact) ----------------
__global__ __launch_bounds__(512, 1) void proj_kernel(
    const float* __restrict__ feat, const float* __restrict__ w_t,
    float* __restrict__ projn) {
  extern __shared__ float smemP[];
  float* fs   = smemP;               // [256 n][68]
  float* wbuf = smemP + NN * FS_STR; // [64 n][132]
  int b = blockIdx.x >> 6;
  int t0 = (blockIdx.x & 63) << 6;
  int tid = threadIdx.x;
  int td = tid & 31, tt = tid >> 5;

  float acc[4][4];
#pragma unroll
  for (int i = 0; i < 4; ++i)
#pragma unroll
    for (int j = 0; j < 4; ++j) acc[i][j] = 0.f;

  for (int c = 0; c < 4; ++c) {
    if (c) __syncthreads();
#pragma unroll
    for (int k = 0; k < 4; ++k) {
      int slot = tid + k * 512;
      int n = slot >> 5, d4 = slot & 31;
      *(float4*)(wbuf + n * WB_STR + d4 * 4) =
          *(const float4*)(w_t + (size_t)(c * 64 + n) * DD + d4 * 4);
    }
    if (c == 0) {
#pragma unroll
      for (int k = 0; k < 8; ++k) {
        int slot = tid + k * 512;
        int n = slot >> 4, t4 = slot & 15;
        *(float4*)(fs + n * FS_STR + t4 * 4) =
            *(const float4*)(feat + ((size_t)(b * NN + n)) * TT + t0 + t4 * 4);
      }
    }
    __syncthreads();

    const float* fp = fs + (c * 64) * FS_STR + tt * 4;
    const float* wp = wbuf + td * 4;
#pragma unroll 4
    for (int n = 0; n < 64; ++n) {
      float4 f = *(const float4*)(fp + n * FS_STR);
      float4 wv = *(const float4*)(wp + n * WB_STR);
      float fa[4] = {f.x, f.y, f.z, f.w};
#pragma unroll
      for (int i = 0; i < 4; ++i) {
        acc[i][0] += fa[i] * wv.x;
        acc[i][1] += fa[i] * wv.y;
        acc[i][2] += fa[i] * wv.z;
        acc[i][3] += fa[i] * wv.w;
      }
    }
  }

  float s[4];
#pragma unroll
  for (int i = 0; i < 4; ++i)
    s[i] = acc[i][0] * acc[i][0] + acc[i][1] * acc[i][1] +
           acc[i][2] * acc[i][2] + acc[i][3] * acc[i][3];
#pragma unroll
  for (int m = 1; m < 32; m <<= 1) {
#pragma unroll
    for (int i = 0; i < 4; ++i) s[i] += __shfl_xor(s[i], m, 64);
  }
#pragma unroll
  for (int i = 0; i < 4; ++i) {
    float inv = 1.0f / fmaxf(sqrtf(s[i]), 1e-12f);
    float4 o;
    o.x = acc[i][0] * inv; o.y = acc[i][1] * inv;
    o.z = acc[i][2] * inv; o.w = acc[i][3] * inv;
    *(float4*)(projn + ((size_t)(b * TT + t0 + tt * 4 + i)) * DD + td * 4) = o;
  }
}

// ---------------- kernel 4: banded cosine sims + FC + ReLU (R8-f32 exact) ----------------
__global__ __launch_bounds__(512, 1) void band_fc_kernel(
    const float* __restrict__ projn, const float* __restrict__ wfc_t,
    const float* __restrict__ b_fc, float* __restrict__ out) {
  extern __shared__ float4 smemC[];
  float4* p4 = smemC;                            // [ROWS][RSTR]
  float* band = (float*)(smemC + ROWS * RSTR);   // [64][101]
  int b = blockIdx.x >> 6;
  int t0 = (blockIdx.x & 63) << 6;
  int tid = threadIdx.x;

  const float4* pg = (const float4*)projn;
  for (int i = tid; i < ROWS * 32; i += 512) {
    int r = i >> 5, c = i & 31;
    int t = t0 + r - PADK;
    float4 v = make_float4(0.f, 0.f, 0.f, 0.f);
    if (t >= 0 && t < TT) v = pg[(((size_t)b * TT + t) << 5) + c];
    p4[r * RSTR + c] = v;
  }
  __syncthreads();

  int w = tid >> 6, tt = tid & 63;

  float4 own[32];
#pragma unroll
  for (int c = 0; c < 32; ++c) own[c] = p4[(tt + PADK) * RSTR + c];

  int s0 = w * 21;
  int sEnd = (s0 + 21 < ROWS) ? (s0 + 21) : ROWS;
  for (int s = s0; s < sEnd; ++s) {
    float a0 = 0.f, a1 = 0.f, a2 = 0.f, a3 = 0.f;  // 4 independent chains
#pragma unroll
    for (int c = 0; c < 32; ++c) {
      float4 ov = p4[s * RSTR + c];   // wave-uniform -> LDS broadcast
      a0 += own[c].x * ov.x;
      a1 += own[c].y * ov.y;
      a2 += own[c].z * ov.z;
      a3 += own[c].w * ov.w;
    }
    int j = s - tt;
    if (j >= 0 && j < LK) band[tt * LK + j] = (a0 + a1) + (a2 + a3);
  }
  __syncthreads();

  int o0u = __builtin_amdgcn_readfirstlane((tid >> 6) * 16);
  float acc[16];
  const float4* bf4 = (const float4*)(b_fc + o0u);
#pragma unroll
  for (int k = 0; k < 4; ++k) {
    float4 bv = bf4[k];
    acc[4 * k + 0] = bv.x; acc[4 * k + 1] = bv.y;
    acc[4 * k + 2] = bv.z; acc[4 * k + 3] = bv.w;
  }
#pragma unroll 2
  for (int j = 0; j < LK; ++j) {
    float bv = band[tt * LK + j];                 // gcd(101,32)=1: conflict-free
    const float4* wr = (const float4*)(wfc_t + j * OD + o0u);  // uniform
#pragma unroll
    for (int k = 0; k < 4; ++k) {
      float4 wv = wr[k];
      acc[4 * k + 0] += wv.x * bv;
      acc[4 * k + 1] += wv.y * bv;
      acc[4 * k + 2] += wv.z * bv;
      acc[4 * k + 3] += wv.w * bv;
    }
  }
  float4* og = (float4*)(out + ((size_t)(b * TT + t0 + tt)) * OD + o0u);
#pragma unroll
  for (int k = 0; k < 4; ++k) {
    float4 o;
    o.x = fmaxf(acc[4 * k + 0], 0.f);
    o.y = fmaxf(acc[4 * k + 1], 0.f);
    o.z = fmaxf(acc[4 * k + 2], 0.f);
    o.w = fmaxf(acc[4 * k + 3], 0.f);
    og[k] = o;
  }
}

extern "C" void kernel_launch(void* const* d_in, const int* in_sizes, int n_in,
                              void* d_out, int out_size, void* d_ws, size_t ws_size,
                              hipStream_t stream) {
  const float* x      = (const float*)d_in[0];
  const float* w_proj = (const float*)d_in[1];
  const float* w_fc   = (const float*)d_in[2];
  const float* b_fc   = (const float*)d_in[3];
  float* out = (float*)d_out;

  char* ws = (char*)d_ws;
  float* feat  = (float*)ws;                                    // B*N*T f32  = 16,777,216 B
  float* projn = (float*)(ws + 16777216);                       // B*T*D f32  =  8,388,608 B
  float* w_t   = (float*)(ws + 16777216 + 8388608);             // N*D f32    =    131,072 B
  float* wfc_t = (float*)(ws + 16777216 + 8388608 + 131072);    // LK*OD f32  =     51,712 B

  size_t smP = (size_t)(NN * FS_STR + 64 * WB_STR) * sizeof(float);                    // 103,424 B
  size_t smC = (size_t)ROWS * RSTR * sizeof(float4) + (size_t)64 * LK * sizeof(float); // 112,448 B
  (void)hipFuncSetAttribute((const void*)proj_kernel,
                      hipFuncAttributeMaxDynamicSharedMemorySize, (int)smP);
  (void)hipFuncSetAttribute((const void*)band_fc_kernel,
                      hipFuncAttributeMaxDynamicSharedMemorySize, (int)smC);

  transpose_w_kernel<<<64, 256, 0, stream>>>(w_proj, w_fc, w_t, wfc_t);
  pool_kernel<<<(BB * NN * TT) / 512, 256, 0, stream>>>(x, feat);
  proj_kernel<<<BB * (TT / 64), 512, smP, stream>>>(feat, w_t, projn);
  band_fc_kernel<<<BB * (TT / 64), 512, smC, stream>>>(projn, wfc_t, b_fc, out);
}